// Round 2
// baseline (528.302 us; speedup 1.0000x reference)
//
#include <hip/hip_runtime.h>
#include <math.h>

#define N_ROWS 32768
#define DIM    1024
#define NE     64
#define KTOP   8

// v3: LDS-tiled, 8x8-register-blocked GEMM front-end.
//
// Diagnosis (v0 counters): w fed via s_load -> 256KB/CU streamed through the
// ~16KB scalar K$ -> serialized ~260cyc misses -> VALUBusy 23%, 222us vs the
// 27us FMA floor. Fix: feed BOTH operands through LDS with enough register
// reuse that the LDS pipe keeps up: lane (er,rr) owns an 8-row x 8-expert
// accumulator tile; per k-step it reads 8 x-floats + 8 w-floats (4x
// ds_read_b128) for 64 FMAs = 1 B per lane-FMA ~= 128 B/cyc/CU at full VALU
// rate (LDS-bound ~35us main loop).
//
// Tiles are k-major [64k][64r|64e] with XOR swizzle: float (k, r) stored at
// word k*64 + 4*((r>>2) ^ (k>>3)) + (r&3). Reads for (rr, k=j*8+wid) become
// two contiguous b128s at k*64 + 8*(rr^(j>>1)) (+4), halves swapped when
// (j&1) - all compile-time per unrolled j. Every LDS access pattern (stage
// writes, fragment reads, reduction) is <=2-way on banks (free, m136).
//
// k-split: wave wid owns k = 64*rc + 8*j + wid; 8-wave reduction + epilogue
// reuse the v0-proven code. Static LDS = 33.8 KB (v2's 65,540 B static LDS
// exceeded the 64 KB cap -> container failure; also dropped global_load_lds).

extern "C" __global__ void __launch_bounds__(512, 4)
moe_gate_kernel(const float* __restrict__ x, const float* __restrict__ gw,
                const float* __restrict__ nw, const float* __restrict__ noise,
                float* __restrict__ out0, float* __restrict__ out1,
                float* __restrict__ lossp,
                double* __restrict__ esum, int* __restrict__ ticket) {
    __shared__ __align__(16) float smem[8448];   // 33,792 B
    __shared__ int isLast;
    float* xt  = smem;            // [4096] swizzled x-tile   (later: red)
    float* wt  = smem + 4096;     // [4096] swizzled w-tile   (later: lg)
    float* red = smem;            // [4096] k-split reduction scratch
    float* lg  = smem + 4096;     // [64*65 = 4160] logits    (8256 <= 8448)

    const int tid  = threadIdx.x;
    const int lane = tid & 63;
    const int wid  = __builtin_amdgcn_readfirstlane(tid >> 6);   // 0..7
    const int er   = lane >> 3;       // expert-group: experts er*8 + n
    const int rr   = lane & 7;        // row-group:    rows    rr*8 + i
    const int row0 = blockIdx.x * 64;

    float acc[8][8];
#pragma unroll
    for (int i = 0; i < 8; ++i)
#pragma unroll
        for (int n = 0; n < 8; ++n) acc[i][n] = 0.f;

    // ---- staging assignment: thread stages 8 x-floats (row sr) and 8
    // w-floats (expert sr) per round, k-window column sc*8..sc*8+7 ----
    const int sr = tid >> 3;          // 0..63
    const int sc = tid & 7;           // 0..7 (= k_local>>3 for its floats)
    const float* gx  = x  + (size_t)(row0 + sr) * DIM + sc * 8;
    const float* gwp = gw + (size_t)sr * DIM + sc * 8;
    const int sbase = sc * 512 + 4 * ((sr >> 2) ^ sc) + (sr & 3); // + q*64

    float px[8], pw[8];
    *(float4*)(px + 0) = *(const float4*)(gx + 0);
    *(float4*)(px + 4) = *(const float4*)(gx + 4);
    *(float4*)(pw + 0) = *(const float4*)(gwp + 0);
    *(float4*)(pw + 4) = *(const float4*)(gwp + 4);

    // per-lane read bases for the 4 XOR values c1 = j>>1 (word offsets)
    int xbase[4], wbase[4];
#pragma unroll
    for (int c = 0; c < 4; ++c) {
        xbase[c] = wid * 64 + 8 * (rr ^ c);
        wbase[c] = wid * 64 + 8 * (er ^ c);
    }

    // ---- main loop: 16 rounds x 64 k-columns ----
#pragma unroll 1
    for (int rc = 0; rc < 16; ++rc) {
        __syncthreads();              // previous round's tile reads done
#pragma unroll
        for (int q = 0; q < 8; ++q) {           // 2-way banks: free
            xt[sbase + q * 64] = px[q];
            wt[sbase + q * 64] = pw[q];
        }
        __syncthreads();              // tiles ready
        if (rc < 15) {                // prefetch next round under compute
            *(float4*)(px + 0) = *(const float4*)(gx + (rc + 1) * 64 + 0);
            *(float4*)(px + 4) = *(const float4*)(gx + (rc + 1) * 64 + 4);
            *(float4*)(pw + 0) = *(const float4*)(gwp + (rc + 1) * 64 + 0);
            *(float4*)(pw + 4) = *(const float4*)(gwp + (rc + 1) * 64 + 4);
        }
#pragma unroll
        for (int j = 0; j < 8; ++j) {           // k = rc*64 + j*8 + wid
            const int c0 = j & 1, c1 = j >> 1;
            const int xw = j * 512 + xbase[c1];
            const int ww = j * 512 + wbase[c1];
            float X0v[4], X1v[4], W0v[4], W1v[4];
            *(float4*)X0v = *(const float4*)(xt + xw);      // rows rr*8+4c0+m
            *(float4*)X1v = *(const float4*)(xt + xw + 4);  // rows rr*8+4(1-c0)+m
            *(float4*)W0v = *(const float4*)(wt + ww);      // exps er*8+4c0+n
            *(float4*)W1v = *(const float4*)(wt + ww + 4);
            const int ra = 4 * c0, rb = 4 - 4 * c0;         // compile-time
#pragma unroll
            for (int m = 0; m < 4; ++m)
#pragma unroll
                for (int n = 0; n < 4; ++n) {
                    acc[ra + m][ra + n] = fmaf(X0v[m], W0v[n], acc[ra + m][ra + n]);
                    acc[ra + m][rb + n] = fmaf(X0v[m], W1v[n], acc[ra + m][rb + n]);
                    acc[rb + m][ra + n] = fmaf(X1v[m], W0v[n], acc[rb + m][ra + n]);
                    acc[rb + m][rb + n] = fmaf(X1v[m], W1v[n], acc[rb + m][rb + n]);
                }
        }
    }

    // ---- k-split reduction: 8 row-slices; all 64 lanes active per slice ----
    __syncthreads();                  // last round's tile reads done
#pragma unroll
    for (int s = 0; s < 8; ++s) {     // fully unrolled: acc[s][*] static
        float4 v0 = make_float4(acc[s][0], acc[s][1], acc[s][2], acc[s][3]);
        float4 v1 = make_float4(acc[s][4], acc[s][5], acc[s][6], acc[s][7]);
        *(float4*)(red + wid * 512 + rr * 64 + er * 8 + 0) = v0;
        *(float4*)(red + wid * 512 + rr * 64 + er * 8 + 4) = v1;
        __syncthreads();
        {
            const int r2 = tid >> 6, e = tid & 63;
            float t = 0.f;
#pragma unroll
            for (int w = 0; w < 8; ++w) t += red[w * 512 + r2 * 64 + e];
            lg[(r2 * 8 + s) * 65 + e] = t;   // row r2*8+s, expert e
        }
        __syncthreads();
    }

    // ---- epilogue: wave handles 8 rows, lane = expert (v0-proven code) ----
    const float nwl = nw[lane];
    float epart = 0.f;

#pragma unroll 1
    for (int i = 0; i < 8; ++i) {
        const int    lrow = wid * 8 + i;
        const size_t grow = (size_t)(row0 + lrow);
        const float  lgv  = lg[lrow * 65 + lane];

        // dense softmax over 64 experts (load-balance mean term)
        float m = lgv;
#pragma unroll
        for (int off = 32; off; off >>= 1) m = fmaxf(m, __shfl_xor(m, off));
        float p = __expf(lgv - m);
        float s = p;
#pragma unroll
        for (int off = 32; off; off >>= 1) s += __shfl_xor(s, off);
        epart += p / s;

        // noisy logits + iterative top-8 argmax (tie -> lower index)
        const float nz    = noise[grow * NE + lane];
        const float noisy = fmaf(nz, nwl, lgv);
        float cur  = noisy;
        bool  sel  = false;
        float mtop = 0.f;
        int   myid = 0;
#pragma unroll
        for (int j = 0; j < KTOP; ++j) {
            float v = cur; int id = lane;
#pragma unroll
            for (int off = 32; off; off >>= 1) {
                float ov = __shfl_xor(v, off);
                int   oi = __shfl_xor(id, off);
                if (ov > v || (ov == v && oi < id)) { v = ov; id = oi; }
            }
            if (j == 0) mtop = v;
            if (lane == id) { sel = true; cur = -INFINITY; }
            if (lane == j) myid = id;
        }

        float swv  = sel ? __expf(noisy - mtop) : 0.f;
        float ssum = swv;
#pragma unroll
        for (int off = 32; off; off >>= 1) ssum += __shfl_xor(ssum, off);

        out0[grow * NE + lane] = swv / ssum;                // coalesced 256 B/row
        if (lane < KTOP) out1[grow * KTOP + lane] = (float)myid;
    }

    // ---- load-balance sums: block partial -> device atomics ----
    __syncthreads();                   // lg reads done; reuse red
    red[wid * 64 + lane] = epart;
    __syncthreads();
    if (tid < NE) {
        float t = 0.f;
#pragma unroll
        for (int w = 0; w < 8; ++w) t += red[w * 64 + tid];
        atomicAdd(&esum[tid], (double)t);
        __threadfence();
    }
    __syncthreads();
    if (tid == 0) {
        int t = atomicAdd(ticket, 1);
        isLast = (t == (int)gridDim.x - 1);
        __threadfence();
    }
    __syncthreads();

    // ---- last block computes the scalar loss (f64) ----
    if (isLast && tid < NE) {
        double v = atomicAdd(&esum[tid], 0.0);    // device-scope read
        double mean = v * (1.0 / 32768.0);
        double d  = mean - (1.0 / 64.0);
        double sq = d * d;
#pragma unroll
        for (int off = 32; off; off >>= 1) sq += __shfl_xor(sq, off);
        if (tid == 0) lossp[0] = (float)(sq * (1.0 / 64.0) * 0.01);
    }
}

extern "C" void kernel_launch(void* const* d_in, const int* in_sizes, int n_in,
                              void* d_out, int out_size, void* d_ws, size_t ws_size,
                              hipStream_t stream) {
    const float* x     = (const float*)d_in[0];   // [32768,1024]
    const float* gw    = (const float*)d_in[1];   // [64,1024]
    const float* nw    = (const float*)d_in[2];   // [64]
    const float* noise = (const float*)d_in[3];   // [32768,64]

    float* out0  = (float*)d_out;                       // [32768,64] gated weights
    float* out1  = out0 + (size_t)N_ROWS * NE;          // [32768,8] ids as f32
    float* lossp = out1 + (size_t)N_ROWS * KTOP;        // scalar loss

    double* esum   = (double*)d_ws;                     // [64]
    int*    ticket = (int*)((char*)d_ws + 512);

    hipMemsetAsync(d_ws, 0, 520, stream);
    moe_gate_kernel<<<N_ROWS / 64, 512, 0, stream>>>(x, gw, nw, noise,
                                                     out0, out1, lossp, esum, ticket);
}